// Round 1
// baseline (517.932 us; speedup 1.0000x reference)
//
#include <hip/hip_runtime.h>
#include <cstdint>

#define N_NODES 50000
#define N_EDGES 800000
#define DIM 64
#define HIDDEN 256

// ---------------------------------------------------------------------------
// Phase 1: scatter-sum of h[src] into agg[dst], plus degree counts.
// 64 threads per edge (one per feature dim), 4 edges per 256-thread block.
// ---------------------------------------------------------------------------
__global__ __launch_bounds__(256)
void scatter_kernel(const float* __restrict__ h,
                    const int* __restrict__ src,
                    const int* __restrict__ dst,
                    float* __restrict__ agg,
                    float* __restrict__ deg) {
    int e = blockIdx.x * 4 + (threadIdx.x >> 6);
    if (e >= N_EDGES) return;
    int d = threadIdx.x & 63;
    int s = src[e];
    int t = dst[e];
    float v = h[s * DIM + d];
    atomicAdd(&agg[t * DIM + d], v);
    if (d == 0) atomicAdd(&deg[t], 1.0f);
}

// ---------------------------------------------------------------------------
// Phase 2: per-node 2-layer MLP with exact-erf GELU.
// One block (256 threads) per node.
//   x[128] = [h[node], agg_mean_or_h[node]]      (LDS)
//   hid[t] = gelu(dot(x, W1[:,t]) + b1[t])       thread t, t in [0,256)
//   out[d] = dot(hid, W2[:,d]) + b2[d]           4-way split over j + reduce
// ---------------------------------------------------------------------------
__global__ __launch_bounds__(256)
void mlp_kernel(const float* __restrict__ h,
                const float* __restrict__ agg,
                const float* __restrict__ deg,
                const float* __restrict__ W1,
                const float* __restrict__ b1,
                const float* __restrict__ W2,
                const float* __restrict__ b2,
                float* __restrict__ out) {
    __shared__ float x[2 * DIM];
    __shared__ float hid[HIDDEN];
    __shared__ float red[256];

    const int node = blockIdx.x;
    const int t = threadIdx.x;

    // Build x = [h, agg/deg (or h where deg==0)]
    if (t < DIM) {
        x[t] = h[node * DIM + t];
    } else if (t < 2 * DIM) {
        int d = t - DIM;
        float dg = deg[node];
        float a = agg[node * DIM + d];
        x[t] = (dg > 0.0f) ? (a / dg) : h[node * DIM + d];
    }
    __syncthreads();

    // Layer 1 + exact GELU: thread t owns hidden unit t.
    float acc = b1[t];
    #pragma unroll
    for (int k = 0; k < 2 * DIM; ++k) {
        acc = fmaf(x[k], W1[k * HIDDEN + t], acc);
    }
    // exact (erf) GELU
    float g = 0.5f * acc * (1.0f + erff(acc * 0.70710678118654752440f));
    hid[t] = g;
    __syncthreads();

    // Layer 2: output dim d = t & 63, partial part = t >> 6 over 64 j's.
    const int d = t & 63;
    const int part = t >> 6;
    float acc2 = 0.0f;
    #pragma unroll
    for (int jj = 0; jj < 64; ++jj) {
        int j = part * 64 + jj;
        acc2 = fmaf(hid[j], W2[j * DIM + d], acc2);
    }
    red[t] = acc2;
    __syncthreads();
    if (t < 64) {
        out[node * DIM + t] =
            red[t] + red[t + 64] + red[t + 128] + red[t + 192] + b2[t];
    }
}

// ---------------------------------------------------------------------------
extern "C" void kernel_launch(void* const* d_in, const int* in_sizes, int n_in,
                              void* d_out, int out_size, void* d_ws, size_t ws_size,
                              hipStream_t stream) {
    const float* h  = (const float*)d_in[0];
    const int* eidx = (const int*)d_in[1];   // [2, N_EDGES]: src row then dst row
    const float* W1 = (const float*)d_in[2];
    const float* b1 = (const float*)d_in[3];
    const float* W2 = (const float*)d_in[4];
    const float* b2 = (const float*)d_in[5];
    float* out = (float*)d_out;

    const int* src = eidx;
    const int* dst = eidx + N_EDGES;

    float* agg = (float*)d_ws;                       // N_NODES * DIM floats
    float* deg = agg + (size_t)N_NODES * DIM;        // N_NODES floats

    // Zero the accumulators every call (harness does not re-poison between
    // replays; we must not rely on leftover state).
    size_t zero_bytes = ((size_t)N_NODES * DIM + N_NODES) * sizeof(float);
    hipMemsetAsync(d_ws, 0, zero_bytes, stream);

    // Phase 1: scatter
    {
        int edges_per_block = 4;
        int grid = (N_EDGES + edges_per_block - 1) / edges_per_block;
        scatter_kernel<<<grid, 256, 0, stream>>>(h, src, dst, agg, deg);
    }

    // Phase 2: MLP
    {
        mlp_kernel<<<N_NODES, 256, 0, stream>>>(h, agg, deg, W1, b1, W2, b2, out);
    }
}

// Round 2
// 346.245 us; speedup vs baseline: 1.4959x; 1.4959x over previous
//
#include <hip/hip_runtime.h>
#include <cstdint>

#define N_NODES 50000
#define N_EDGES 800000
#define DIM 64
#define HIDDEN 256
#define NB 64   // nodes per MLP block
#define KC 16   // k-chunk rows of W1 staged in LDS
#define JC 32   // j-chunk rows of W2 staged in LDS

// ---------------------------------------------------------------------------
// Phase 1: scatter-sum of h[src] into agg[dst], plus degree counts.
// 64 threads per edge (one per feature dim), 4 edges per 256-thread block.
// ---------------------------------------------------------------------------
__global__ __launch_bounds__(256)
void scatter_kernel(const float* __restrict__ h,
                    const int* __restrict__ src,
                    const int* __restrict__ dst,
                    float* __restrict__ agg,
                    float* __restrict__ deg) {
    int e = blockIdx.x * 4 + (threadIdx.x >> 6);
    if (e >= N_EDGES) return;
    int d = threadIdx.x & 63;
    int s = src[e];
    int t = dst[e];
    float v = h[s * DIM + d];
    atomicAdd(&agg[t * DIM + d], v);
    if (d == 0) atomicAdd(&deg[t], 1.0f);
}

// ---------------------------------------------------------------------------
// Phase 2: fused 2-layer MLP, NB=64 nodes per 256-thread block.
//
// LDS (73728 B total -> 2 blocks/CU):
//   region A (65536 B, two overlaid uses):
//     layer 1:  xs[128][64] fp32 (32 KB, XOR-swizzled transpose of x)
//               w1s[KC][256] fp32 (16 KB) at offset 32768
//     layer 2:  hidT[256][64] fp32 (64 KB) - GELU'd hidden, overlays xs/w1s
//   w2s[JC][64] fp32 (8 KB) at offset 65536
//
// Layer 1 thread tile: 8 nodes x 8 hidden  (hg = tid&31 -> j=hg*8.., ng = tid>>5 -> n=ng*8..)
// Layer 2 thread tile: 4 nodes x 4 outputs (dg = tid&15 -> d=dg*4.., ng2 = tid>>4 -> n=ng2*4..)
// ---------------------------------------------------------------------------
__global__ __launch_bounds__(256, 2)
void mlp_kernel(const float* __restrict__ h,
                const float* __restrict__ agg,
                const float* __restrict__ deg,
                const float* __restrict__ W1,
                const float* __restrict__ b1,
                const float* __restrict__ W2,
                const float* __restrict__ b2,
                float* __restrict__ out) {
    __shared__ __align__(16) char lds_raw[73728];
    float* xs   = (float*)lds_raw;             // [128][64], swizzled
    float* w1s  = (float*)(lds_raw + 32768);   // [KC][256]
    float* hidT = (float*)lds_raw;             // [256][64], overlays xs/w1s
    float* w2s  = (float*)(lds_raw + 65536);   // [JC][64]

    const int tid   = threadIdx.x;
    const int node0 = blockIdx.x * NB;

    // ---- build xs = transpose([h | mean_or_h]) with XOR swizzle on n ----
    {
        const int d  = tid & 63;
        const int sw = (d & 3) << 3;   // row k=d and k=64+d share (k&3)
        #pragma unroll
        for (int i = 0; i < 16; ++i) {
            int nn = (tid >> 6) + i * 4;
            int g = node0 + nn;
            if (g >= N_NODES) g = N_NODES - 1;
            float hv = h[g * DIM + d];
            float dgv = deg[g];
            float av = agg[g * DIM + d];
            float xv = (dgv > 0.0f) ? (av / dgv) : hv;
            int nsw = nn ^ sw;
            xs[d * 64 + nsw]        = hv;
            xs[(64 + d) * 64 + nsw] = xv;
        }
    }

    // ---- layer 1: acc1[h][n] ----
    const int hg = tid & 31;
    const int ng = tid >> 5;
    float acc1[8][8];
    #pragma unroll
    for (int a = 0; a < 8; ++a)
        #pragma unroll
        for (int b = 0; b < 8; ++b) acc1[a][b] = 0.0f;

    for (int kc = 0; kc < 128 / KC; ++kc) {
        __syncthreads();  // xs ready (kc=0) / prior w1s readers done (kc>0)
        // stage w1s[KC][256] = 4096 floats, 16 per thread, coalesced
        {
            const float* w1g = W1 + kc * KC * HIDDEN;
            #pragma unroll
            for (int i = 0; i < 4; ++i) {
                int f = tid * 4 + i * 1024;
                *(float4*)&w1s[f] = *(const float4*)&w1g[f];
            }
        }
        __syncthreads();
        #pragma unroll
        for (int kl = 0; kl < KC; ++kl) {
            const int k = kc * KC + kl;
            const int nbase = ((ng ^ (k & 3)) << 3);
            float4 a0 = *(const float4*)&xs[k * 64 + nbase];
            float4 a1 = *(const float4*)&xs[k * 64 + nbase + 4];
            float4 w0 = *(const float4*)&w1s[kl * HIDDEN + hg * 8];
            float4 w1v = *(const float4*)&w1s[kl * HIDDEN + hg * 8 + 4];
            float an[8] = {a0.x, a0.y, a0.z, a0.w, a1.x, a1.y, a1.z, a1.w};
            float wh[8] = {w0.x, w0.y, w0.z, w0.w, w1v.x, w1v.y, w1v.z, w1v.w};
            #pragma unroll
            for (int hh = 0; hh < 8; ++hh)
                #pragma unroll
                for (int nn = 0; nn < 8; ++nn)
                    acc1[hh][nn] = fmaf(wh[hh], an[nn], acc1[hh][nn]);
        }
    }

    // ---- bias + exact GELU, write hidT (overlays xs/w1s) ----
    float4 b1a = *(const float4*)&b1[hg * 8];
    float4 b1b = *(const float4*)&b1[hg * 8 + 4];
    float bv[8] = {b1a.x, b1a.y, b1a.z, b1a.w, b1b.x, b1b.y, b1b.z, b1b.w};
    __syncthreads();  // all xs/w1s reads complete before overwrite
    #pragma unroll
    for (int hh = 0; hh < 8; ++hh) {
        const int j = hg * 8 + hh;
        #pragma unroll
        for (int nn = 0; nn < 8; ++nn) {
            float v = acc1[hh][nn] + bv[hh];
            acc1[hh][nn] = 0.5f * v * (1.0f + erff(v * 0.70710678118654752440f));
        }
        *(float4*)&hidT[j * 64 + ng * 8] =
            make_float4(acc1[hh][0], acc1[hh][1], acc1[hh][2], acc1[hh][3]);
        *(float4*)&hidT[j * 64 + ng * 8 + 4] =
            make_float4(acc1[hh][4], acc1[hh][5], acc1[hh][6], acc1[hh][7]);
    }

    // ---- layer 2: acc2[n][d] ----
    const int dg = tid & 15;
    const int ng2 = tid >> 4;
    float acc2[4][4];
    #pragma unroll
    for (int a = 0; a < 4; ++a)
        #pragma unroll
        for (int b = 0; b < 4; ++b) acc2[a][b] = 0.0f;

    for (int jc = 0; jc < HIDDEN / JC; ++jc) {
        __syncthreads();  // hidT ready (jc=0) / prior w2s readers done (jc>0)
        // stage w2s[JC][64] = 2048 floats, 8 per thread, coalesced
        {
            const float* w2g = W2 + jc * JC * DIM;
            #pragma unroll
            for (int i = 0; i < 2; ++i) {
                int f = tid * 4 + i * 1024;
                *(float4*)&w2s[f] = *(const float4*)&w2g[f];
            }
        }
        __syncthreads();
        #pragma unroll
        for (int jl = 0; jl < JC; ++jl) {
            const int j = jc * JC + jl;
            float4 hv = *(const float4*)&hidT[j * 64 + ng2 * 4];
            float4 wv = *(const float4*)&w2s[jl * 64 + dg * 4];
            acc2[0][0] = fmaf(hv.x, wv.x, acc2[0][0]);
            acc2[0][1] = fmaf(hv.x, wv.y, acc2[0][1]);
            acc2[0][2] = fmaf(hv.x, wv.z, acc2[0][2]);
            acc2[0][3] = fmaf(hv.x, wv.w, acc2[0][3]);
            acc2[1][0] = fmaf(hv.y, wv.x, acc2[1][0]);
            acc2[1][1] = fmaf(hv.y, wv.y, acc2[1][1]);
            acc2[1][2] = fmaf(hv.y, wv.z, acc2[1][2]);
            acc2[1][3] = fmaf(hv.y, wv.w, acc2[1][3]);
            acc2[2][0] = fmaf(hv.z, wv.x, acc2[2][0]);
            acc2[2][1] = fmaf(hv.z, wv.y, acc2[2][1]);
            acc2[2][2] = fmaf(hv.z, wv.z, acc2[2][2]);
            acc2[2][3] = fmaf(hv.z, wv.w, acc2[2][3]);
            acc2[3][0] = fmaf(hv.w, wv.x, acc2[3][0]);
            acc2[3][1] = fmaf(hv.w, wv.y, acc2[3][1]);
            acc2[3][2] = fmaf(hv.w, wv.z, acc2[3][2]);
            acc2[3][3] = fmaf(hv.w, wv.w, acc2[3][3]);
        }
    }

    // ---- output ----
    float4 b2v = *(const float4*)&b2[dg * 4];
    #pragma unroll
    for (int nn = 0; nn < 4; ++nn) {
        int node = node0 + ng2 * 4 + nn;
        if (node < N_NODES) {
            float4 o = make_float4(acc2[nn][0] + b2v.x, acc2[nn][1] + b2v.y,
                                   acc2[nn][2] + b2v.z, acc2[nn][3] + b2v.w);
            *(float4*)&out[node * DIM + dg * 4] = o;
        }
    }
}

// ---------------------------------------------------------------------------
extern "C" void kernel_launch(void* const* d_in, const int* in_sizes, int n_in,
                              void* d_out, int out_size, void* d_ws, size_t ws_size,
                              hipStream_t stream) {
    const float* h  = (const float*)d_in[0];
    const int* eidx = (const int*)d_in[1];   // [2, N_EDGES]: src row then dst row
    const float* W1 = (const float*)d_in[2];
    const float* b1 = (const float*)d_in[3];
    const float* W2 = (const float*)d_in[4];
    const float* b2 = (const float*)d_in[5];
    float* out = (float*)d_out;

    const int* src = eidx;
    const int* dst = eidx + N_EDGES;

    float* agg = (float*)d_ws;                   // N_NODES * DIM floats
    float* deg = agg + (size_t)N_NODES * DIM;    // N_NODES floats

    size_t zero_bytes = ((size_t)N_NODES * DIM + N_NODES) * sizeof(float);
    hipMemsetAsync(d_ws, 0, zero_bytes, stream);

    {
        int grid = (N_EDGES + 3) / 4;
        scatter_kernel<<<grid, 256, 0, stream>>>(h, src, dst, agg, deg);
    }
    {
        int grid = (N_NODES + NB - 1) / NB;
        mlp_kernel<<<grid, 256, 0, stream>>>(h, agg, deg, W1, b1, W2, b2, out);
    }
}